// Round 1
// baseline (705.972 us; speedup 1.0000x reference)
//
#include <hip/hip_runtime.h>

// EmbedLoopyBP on gfx950 — round 9.
// R8 + barrier-free k_iter/k_im: Wc^T / We^T are pre-arranged in MFMA
// B-fragment order in global (L1/L2-hot, 8KB/4KB) so the only cross-wave
// LDS staging (and its __syncthreads) disappears. LDS/block 26.6->17.9KB
// -> 8 blocks/CU (thread-capped). k_cvt dispatches dropped: naW is read
// directly as fp32 (gathers are L3-resident); re-zero via one memsetAsync.

#define NN 50000
#define NE 800000
#define NG 128
#define D 64
#define LDE 36
#define LDW 66
#define LDO 72

typedef unsigned short u16;
typedef unsigned int u32;
typedef __bf16 bf16x8 __attribute__((ext_vector_type(8)));
typedef float f32x4 __attribute__((ext_vector_type(4)));

__device__ __forceinline__ float b2f(u16 u){ u32 x=((u32)u)<<16; float f; __builtin_memcpy(&f,&x,4); return f; }
__device__ __forceinline__ u16 f2b(float f){ u32 x; __builtin_memcpy(&x,&f,4); x += 0x7fffu + ((x>>16)&1u); return (u16)(x>>16); }
__device__ __forceinline__ u32 pack2(float a, float b){ return (u32)f2b(a) | ((u32)f2b(b)<<16); }
__device__ __forceinline__ void unpack8(uint4 v, float* o){
  o[0]=b2f((u16)(v.x&0xffffu)); o[1]=b2f((u16)(v.x>>16));
  o[2]=b2f((u16)(v.y&0xffffu)); o[3]=b2f((u16)(v.y>>16));
  o[4]=b2f((u16)(v.z&0xffffu)); o[5]=b2f((u16)(v.z>>16));
  o[6]=b2f((u16)(v.w&0xffffu)); o[7]=b2f((u16)(v.w>>16));
}

// ---------------- one-time weight fragment-order convert ----------------
// wcB[nt][h][j][kk] (4x2x64x8 u16): lane j of the MFMA wave loads its B
// fragment for tile nt, K-half h as 8 contiguous bf16 at wcB+nt*1024+h*512+j*8.
//   j = q*16+mr (q=lane>>4, mr=lane&15); element kk -> Wc[(h*32+q*8+kk)*D + nt*16+mr]
// weB[nt][j][kk] (4x64x8 u16): K=32, element kk -> We[(q*8+kk)*D + nt*16+mr]
__global__ __launch_bounds__(256) void k_prep(const float* __restrict__ Wc, const float* __restrict__ We,
                                              u16* __restrict__ wcB, u16* __restrict__ weB){
  int i = blockIdx.x*256 + threadIdx.x;
  if (i < 4096){
    int nt = i>>10, r = i&1023;
    int h = r>>9, r2 = r&511;
    int j = r2>>3, kk = r2&7;
    int row = nt*16 + (j&15);
    int k = h*32 + (j>>4)*8 + kk;
    wcB[i] = f2b(Wc[k*D + row]);
  }
  int t = i - 4096;
  if (t >= 0 && t < 2048){
    int nt = t>>9, r = t&511;
    int j = r>>3, kk = r&7;
    int row = nt*16 + (j&15);
    int k = (j>>4)*8 + kk;
    weB[t] = f2b(We[k*D + row]);
  }
}

// ---------------- node linear: inlb = bf16(node_feat @ Wn + bn) ----------------
__global__ __launch_bounds__(256) void k_inl(const float* __restrict__ nf, const float* __restrict__ Wn,
                                             const float* __restrict__ bn, u16* __restrict__ inlb){
  __shared__ float w[D*D];
  for (int i=threadIdx.x;i<D*D;i+=256) w[i]=Wn[i];
  __syncthreads();
  const int d = threadIdx.x&63;
  const int n = blockIdx.x*4 + (threadIdx.x>>6);
  if (n>=NN) return;
  float v = bn[d];
  const float* row = nf + (size_t)n*D;
  #pragma unroll 8
  for (int k=0;k<D;k++) v += row[k]*w[k*D+d];
  inlb[(size_t)n*D+d] = f2b(v);
}

// ---------------- imP[perm[e]] = edge_feat@We + be + inl[src[e]]  (bf16) ----------------
// barrier-free: efs rows + os rows are wave-local; B comes from global weB (L1-hot)
__global__ __launch_bounds__(256) void k_im(const float* __restrict__ ef, const u16* __restrict__ weB,
                                            const float* __restrict__ be, const u16* __restrict__ inlb,
                                            const int* __restrict__ src, const int* __restrict__ perm,
                                            u16* __restrict__ imP){
  __shared__ __align__(16) u16 efs[64*LDE];
  __shared__ float os[64*68];
  const int t = threadIdx.x;
  const int ebase = blockIdx.x*64;
  { // stage edge_feat bf16 (coalesced float4 reads); wave-local rows
    int e=t>>2, k0=(t&3)*8;
    const float* p = ef + (size_t)(ebase+e)*32 + k0;
    float4 v0=*(const float4*)p, v1=*(const float4*)(p+4);
    uint4 pk = make_uint4(pack2(v0.x,v0.y),pack2(v0.z,v0.w),pack2(v1.x,v1.y),pack2(v1.z,v1.w));
    *(uint4*)&efs[e*LDE + k0] = pk;
  }
  { // MFMA 16x16x32 (K=32, one step); B fragments from global, coalesced
    int w=t>>6, lane=t&63, q=lane>>4, mr=lane&15;
    int rowb=w*16;
    bf16x8 A = *(const bf16x8*)&efs[(rowb+mr)*LDE + q*8];
    #pragma unroll
    for (int nt=0;nt<4;nt++){
      bf16x8 B = *(const bf16x8*)(weB + nt*512 + lane*8);
      f32x4 acc = {0.f,0.f,0.f,0.f};
      acc = __builtin_amdgcn_mfma_f32_16x16x32_bf16(A,B,acc,0,0,0);
      #pragma unroll
      for (int r=0;r<4;r++) os[(rowb+q*4+r)*68 + nt*16+mr] = acc[r];
    }
  }
  { // epilogue: + be + inlb[src[e]] -> bf16, full-row scatter to imP[perm[e]]
    int e=t>>2, d0=(t&3)*16;
    const size_t eg = (size_t)(ebase+e);
    const int s = src[eg], ps = perm[eg];
    const u16* ip = inlb + (size_t)s*D + d0;
    uint4 iv0 = *(const uint4*)ip, iv1 = *(const uint4*)(ip+8);
    float il[16]; unpack8(iv0,il); unpack8(iv1,il+8);
    float x[16];
    #pragma unroll
    for (int j=0;j<16;j++) x[j] = os[e*68 + d0 + j] + be[d0+j] + il[j];
    uint4 p0 = make_uint4(pack2(x[0],x[1]),pack2(x[2],x[3]),pack2(x[4],x[5]),pack2(x[6],x[7]));
    uint4 p1 = make_uint4(pack2(x[8],x[9]),pack2(x[10],x[11]),pack2(x[12],x[13]),pack2(x[14],x[15]));
    u16* op = imP + (size_t)ps*D + d0;
    *(uint4*)op = p0; *(uint4*)(op+8) = p1;
  }
}

// ---------------- iteration kernel: 64 slots/block, ZERO barriers ----------------
// MODE 0: x=relu(imP[slot]);                                  revOut[prevP[slot]]=(x@Wc); naW_out += per-node
// MODE 1: x=relu(naW[srcP] (fp32) - revIn[slot]+bc+imP[slot]); same outputs
template<int MODE>
__global__ __launch_bounds__(256) void k_iter(const u16* __restrict__ imP, const u16* __restrict__ revIn,
      const float* __restrict__ naW, const u16* __restrict__ wcB, const float* __restrict__ bc,
      const int* __restrict__ srcP, const int* __restrict__ prevP, const int* __restrict__ nodeP,
      u16* __restrict__ revOut, float* __restrict__ naW_out){
  __shared__ __align__(16) u16 xs[64*LDW];
  __shared__ __align__(16) u16 os[64*LDO];
  __shared__ int nid[64];
  const int t = threadIdx.x;
  const int lane = t&63, w = t>>6;
  const size_t sbase = (size_t)blockIdx.x*64;
  if (lane < 16) nid[w*16 + lane] = nodeP[sbase + w*16 + lane];   // wave-local
  { // phase 1: streams + naW fp32 gather; xs rows wave-local
    const int e = t>>2, d0 = (t&3)*16;
    const size_t slot = sbase + e;
    const u16* ip = imP + slot*D + d0;
    uint4 r0 = *(const uint4*)ip, r1 = *(const uint4*)(ip+8);
    float x[16]; unpack8(r0,x); unpack8(r1,x+8);
    if (MODE == 1){
      const int sp = srcP[slot];
      const u16* cp = revIn + slot*D + d0;
      uint4 c0=*(const uint4*)cp, c1=*(const uint4*)(cp+8);
      float nv[16];
      { const float* np_ = naW + (size_t)sp*D + d0;
        *(float4*)&nv[0]  = *(const float4*)np_;
        *(float4*)&nv[4]  = *(const float4*)(np_+4);
        *(float4*)&nv[8]  = *(const float4*)(np_+8);
        *(float4*)&nv[12] = *(const float4*)(np_+12);
      }
      float cv[16];
      unpack8(c0,cv); unpack8(c1,cv+8);
      #pragma unroll
      for (int j=0;j<16;j++) x[j] += nv[j] - cv[j] + bc[d0+j];
    }
    #pragma unroll
    for (int j=0;j<16;j++) x[j] = x[j]>0.f ? x[j] : 0.f;
    uint4 p0 = make_uint4(pack2(x[0],x[1]),pack2(x[2],x[3]),pack2(x[4],x[5]),pack2(x[6],x[7]));
    uint4 p1 = make_uint4(pack2(x[8],x[9]),pack2(x[10],x[11]),pack2(x[12],x[13]),pack2(x[14],x[15]));
    u16* qd = &xs[e*LDW + d0];
    *(uint4*)qd = p0; *(uint4*)(qd+8) = p1;
  }
  { // phase 2: MFMA (xs wave-local, within-wave LDS ordering); B from global wcB
    const int q = lane>>4, mr = lane&15;
    const int rowb = w*16;
    bf16x8 A0 = *(const bf16x8*)&xs[(rowb+mr)*LDW + q*8];
    bf16x8 A1 = *(const bf16x8*)&xs[(rowb+mr)*LDW + 32 + q*8];
    #pragma unroll
    for (int nt=0;nt<4;nt++){
      bf16x8 B0 = *(const bf16x8*)(wcB + nt*1024 + lane*8);
      bf16x8 B1 = *(const bf16x8*)(wcB + nt*1024 + 512 + lane*8);
      f32x4 acc = {0.f,0.f,0.f,0.f};
      acc = __builtin_amdgcn_mfma_f32_16x16x32_bf16(A0,B0,acc,0,0,0);
      acc = __builtin_amdgcn_mfma_f32_16x16x32_bf16(A1,B1,acc,0,0,0);
      #pragma unroll
      for (int r=0;r<4;r++) os[(rowb+q*4+r)*LDO + nt*16 + mr] = f2b(acc[r]);
    }
    const int lr = lane>>2, cc = lane&3;
    const int tgt = prevP[sbase + rowb + lr];
    u16* gp = revOut + (size_t)tgt*D + cc*16;
    *(uint4*)gp     = *(const uint4*)&os[(rowb+lr)*LDO + cc*16];
    *(uint4*)(gp+8) = *(const uint4*)&os[(rowb+lr)*LDO + cc*16 + 8];
    // fused per-node reduction (wave-local os + nid)
    float acc = 0.f;
    int curn = nid[rowb];
    #pragma unroll 4
    for (int i=0;i<16;++i){
      int n = nid[rowb+i];                 // wave-uniform
      if (n != curn){
        atomicAdd(&naW_out[(size_t)curn*D + lane], acc);
        curn = n; acc = 0.f;
      }
      acc += b2f(os[(rowb+i)*LDO + lane]);
    }
    atomicAdd(&naW_out[(size_t)curn*D + lane], acc);
  }
}

// ---------------- final BP step (barrier-free): e2n += per-node ----------------
__global__ __launch_bounds__(256) void k_last(const u16* __restrict__ imP, const u16* __restrict__ revIn,
      const float* __restrict__ naW, const float* __restrict__ bc,
      const int* __restrict__ srcP, const int* __restrict__ nodeP,
      float* __restrict__ e2n){
  __shared__ __align__(16) u16 xs[64*LDW];
  __shared__ int nid[64];
  const int t = threadIdx.x;
  const int lane = t&63, w = t>>6;
  const size_t sbase = (size_t)blockIdx.x*64;
  if (lane < 16) nid[w*16+lane] = nodeP[sbase + w*16 + lane];   // wave-local
  {
    const int e = t>>2, d0 = (t&3)*16;
    const size_t slot = sbase + e;
    const u16* ip = imP + slot*D + d0;
    uint4 r0 = *(const uint4*)ip, r1 = *(const uint4*)(ip+8);
    float x[16]; unpack8(r0,x); unpack8(r1,x+8);
    const int sp = srcP[slot];
    const u16* cp = revIn + slot*D + d0;
    uint4 c0 = *(const uint4*)cp, c1 = *(const uint4*)(cp+8);
    float nv[16];
    { const float* np_ = naW + (size_t)sp*D + d0;
      *(float4*)&nv[0]  = *(const float4*)np_;
      *(float4*)&nv[4]  = *(const float4*)(np_+4);
      *(float4*)&nv[8]  = *(const float4*)(np_+8);
      *(float4*)&nv[12] = *(const float4*)(np_+12);
    }
    float cv[16];
    unpack8(c0,cv); unpack8(c1,cv+8);
    #pragma unroll
    for (int j=0;j<16;j++){ x[j] += nv[j] - cv[j] + bc[d0+j]; x[j] = x[j]>0.f ? x[j] : 0.f; }
    uint4 p0 = make_uint4(pack2(x[0],x[1]),pack2(x[2],x[3]),pack2(x[4],x[5]),pack2(x[6],x[7]));
    uint4 p1 = make_uint4(pack2(x[8],x[9]),pack2(x[10],x[11]),pack2(x[12],x[13]),pack2(x[14],x[15]));
    u16* qd = &xs[e*LDW + d0];
    *(uint4*)qd = p0; *(uint4*)(qd+8) = p1;
  }
  { // wave-local reduction, no barrier
    float acc = 0.f;
    int curn = nid[w*16];
    #pragma unroll 4
    for (int i=0;i<16;++i){
      int n = nid[w*16+i];
      if (n != curn){
        atomicAdd(&e2n[(size_t)curn*D + lane], acc);
        curn = n; acc = 0.f;
      }
      acc += b2f(xs[(w*16+i)*LDW + lane]);
    }
    atomicAdd(&e2n[(size_t)curn*D + lane], acc);
  }
}

// ---------------- CSR build ----------------
__global__ void k_hist(const int* __restrict__ dst, int* __restrict__ cnt){
  int e = blockIdx.x*256 + threadIdx.x;
  atomicAdd(&cnt[dst[e]], 1);
}
__global__ __launch_bounds__(1024) void k_scan1(const int* __restrict__ cnt, int* __restrict__ outv,
                                                int* __restrict__ bsums, int n){
  __shared__ int sh[1024];
  int i = blockIdx.x*1024 + threadIdx.x;
  int v = (i<n)? cnt[i] : 0;
  sh[threadIdx.x]=v;
  __syncthreads();
  for (int off=1; off<1024; off<<=1){
    int tv = (threadIdx.x>=(unsigned)off)? sh[threadIdx.x-off] : 0;
    __syncthreads();
    sh[threadIdx.x] += tv;
    __syncthreads();
  }
  if (i<n) outv[i] = sh[threadIdx.x] - v;
  if (threadIdx.x==1023) bsums[blockIdx.x] = sh[1023];
}
__global__ __launch_bounds__(1024) void k_scan3(int* __restrict__ off, int* __restrict__ cur,
                                                const int* __restrict__ bsums, int n){
  __shared__ int spref;
  if (threadIdx.x < 64){
    int v = ((int)threadIdx.x < (int)blockIdx.x) ? bsums[threadIdx.x] : 0;
    #pragma unroll
    for (int o=1;o<64;o<<=1) v += __shfl_xor(v, o, 64);
    if (threadIdx.x==0) spref = v;
  }
  __syncthreads();
  int i = blockIdx.x*1024 + threadIdx.x;
  if (i<n){ int v = off[i] + spref; off[i]=v; cur[i]=v; }
}
__global__ void k_fill(const int* __restrict__ dst, const int* __restrict__ src,
                       int* __restrict__ cur, int* __restrict__ perm,
                       int* __restrict__ srcP, int* __restrict__ nodeP){
  int e = blockIdx.x*256 + threadIdx.x;
  int d = dst[e];
  int pos = atomicAdd(&cur[d], 1);
  perm[e] = pos;
  srcP[pos] = src[e];
  nodeP[pos] = d;
}
__global__ void k_prev(const int* __restrict__ rev, const int* __restrict__ perm, int* __restrict__ prevP){
  int e = blockIdx.x*256 + threadIdx.x;
  prevP[perm[e]] = perm[rev[e]];
}

// ---------------- final: relu(e2n)@Wo+bo -> relu -> graph segsum ----------------
__global__ __launch_bounds__(256) void k_final(const float* __restrict__ e2n, const float* __restrict__ Wo,
                                               const float* __restrict__ bo, const int* __restrict__ gid,
                                               float* __restrict__ yacc){
  __shared__ float w[D*D];
  for (int i=threadIdx.x;i<D*D;i+=256) w[i]=Wo[i];
  __syncthreads();
  const int d = threadIdx.x&63, sub = threadIdx.x>>6;
  const int n0 = blockIdx.x*32 + sub*8;
  const float bod = bo[d];
  float acc=0.f; int curg=-1;
  for (int i=0;i<8;i++){
    int n=n0+i;
    if (n>=NN) break;
    int g = gid[n];
    if (g!=curg){ if (curg>=0) atomicAdd(&yacc[curg*D+d], acc); curg=g; acc=0.f; }
    float v=bod;
    const float* er = e2n + (size_t)n*D;
    #pragma unroll 8
    for (int k=0;k<D;k++){ float h=er[k]; h = h>0.f?h:0.f; v += h*w[k*D+d]; }
    acc += (v>0.f ? v : 0.f);
  }
  if (curg>=0) atomicAdd(&yacc[curg*D+d], acc);
}
__global__ void k_out(const float* __restrict__ yacc, float* __restrict__ outp){
  int i = blockIdx.x*256 + threadIdx.x;
  if (i<NG*D){ float v=yacc[i]; outp[i]= v>0.f?v:0.f; }
}

// ---------------- workspace layout (unchanged from R8; NAB now unused) ----------------
static constexpr size_t SZ_E   = (size_t)NE*D*2;          // 102.4 MB bf16 edge array
static constexpr size_t SZ_NF4 = (size_t)NN*D*4;          // 12.8 MB fp32 node array
static constexpr size_t SZ_NB  = (size_t)NN*D*2;          // 6.4 MB bf16 node array
static constexpr size_t OFF_IMP  = 0;
static constexpr size_t OFF_RVA  = SZ_E;
static constexpr size_t OFF_RVB  = 2*SZ_E;
// contiguous zero region: csr_cur | naW0 | naW1 | e2n | yacc
static constexpr size_t OFF_CCUR = 3*SZ_E;
static constexpr size_t OFF_NA0  = OFF_CCUR + 200064;
static constexpr size_t OFF_NA1  = OFF_NA0 + SZ_NF4;
static constexpr size_t OFF_E2N  = OFF_NA1 + SZ_NF4;
static constexpr size_t OFF_YACC = OFF_E2N + SZ_NF4;
static constexpr size_t ZERO_SZ  = 200064 + 3*SZ_NF4 + (size_t)NG*D*4;
static constexpr size_t OFF_NAB  = OFF_YACC + (size_t)NG*D*4;   // (unused, keeps layout stable)
static constexpr size_t OFF_INL  = OFF_NAB + SZ_NB;
static constexpr size_t OFF_COFF = OFF_INL + SZ_NB;
static constexpr size_t OFF_PERM = OFF_COFF + 200064;
static constexpr size_t OFF_SRCP = OFF_PERM + (size_t)NE*4;
static constexpr size_t OFF_PRVP = OFF_SRCP + (size_t)NE*4;
static constexpr size_t OFF_NODP = OFF_PRVP + (size_t)NE*4;
static constexpr size_t OFF_BS   = OFF_NODP + (size_t)NE*4;
static constexpr size_t OFF_WCT  = OFF_BS + 256;               // wcB: 4096 u16 = 8192 B
static constexpr size_t OFF_WET  = OFF_WCT + 8192;             // weB: 2048 u16 = 4096 B

extern "C" void kernel_launch(void* const* d_in, const int* in_sizes, int n_in,
                              void* d_out, int out_size, void* d_ws, size_t ws_size,
                              hipStream_t stream) {
  const float* node_feat = (const float*)d_in[0];
  const float* edge_feat = (const float*)d_in[1];
  const int*   src       = (const int*)d_in[2];
  const int*   dst       = (const int*)d_in[3];
  const int*   rev       = (const int*)d_in[4];
  const int*   gid       = (const int*)d_in[5];
  const float* Wn = (const float*)d_in[7];
  const float* bn = (const float*)d_in[8];
  const float* We = (const float*)d_in[9];
  const float* be = (const float*)d_in[10];
  const float* Wc = (const float*)d_in[11];
  const float* bc = (const float*)d_in[12];
  const float* Wo = (const float*)d_in[13];
  const float* bo = (const float*)d_in[14];

  char* ws = (char*)d_ws;
  u16*   imP     = (u16*)(ws + OFF_IMP);
  u16*   revA    = (u16*)(ws + OFF_RVA);
  u16*   revB    = (u16*)(ws + OFF_RVB);
  float* naW0    = (float*)(ws + OFF_NA0);
  float* naW1    = (float*)(ws + OFF_NA1);
  float* e2n     = (float*)(ws + OFF_E2N);
  float* yacc    = (float*)(ws + OFF_YACC);
  u16*   inlb    = (u16*)(ws + OFF_INL);
  int*   csr_off = (int*)(ws + OFF_COFF);
  int*   csr_cur = (int*)(ws + OFF_CCUR);
  int*   perm    = (int*)(ws + OFF_PERM);
  int*   srcP    = (int*)(ws + OFF_SRCP);
  int*   prevP   = (int*)(ws + OFF_PRVP);
  int*   nodeP   = (int*)(ws + OFF_NODP);
  int*   bsums   = (int*)(ws + OFF_BS);
  u16*   wcB     = (u16*)(ws + OFF_WCT);
  u16*   weB     = (u16*)(ws + OFF_WET);

  // one upfront memset: csr_cur + naW0 + naW1 + e2n + yacc
  hipMemsetAsync(ws + OFF_CCUR, 0, ZERO_SZ, stream);

  // CSR build
  k_hist <<<NE/256, 256, 0, stream>>>(dst, csr_cur);
  k_scan1<<<49, 1024, 0, stream>>>(csr_cur, csr_off, bsums, NN);
  k_scan3<<<49, 1024, 0, stream>>>(csr_off, csr_cur, bsums, NN);
  k_fill <<<NE/256, 256, 0, stream>>>(dst, src, csr_cur, perm, srcP, nodeP);
  k_prev <<<NE/256, 256, 0, stream>>>(rev, perm, prevP);

  // weights prep + front end
  k_prep<<<24, 256, 0, stream>>>(Wc, We, wcB, weB);
  k_inl <<<NN/4, 256, 0, stream>>>(node_feat, Wn, bn, inlb);
  k_im  <<<NE/64, 256, 0, stream>>>(edge_feat, weB, be, inlb, src, perm, imP);

  // loopy BP (naW consumed directly as fp32; no k_cvt round trips)
  k_iter<0><<<NE/64, 256, 0, stream>>>(imP, revA, naW1, wcB, bc, srcP, prevP, nodeP, revA, naW0);
  k_iter<1><<<NE/64, 256, 0, stream>>>(imP, revA, naW0, wcB, bc, srcP, prevP, nodeP, revB, naW1);
  hipMemsetAsync(ws + OFF_NA0, 0, SZ_NF4, stream);   // re-zero naW0 for 3rd accumulation
  k_iter<1><<<NE/64, 256, 0, stream>>>(imP, revB, naW1, wcB, bc, srcP, prevP, nodeP, revA, naW0);
  k_last<<<NE/64, 256, 0, stream>>>(imP, revA, naW0, bc, srcP, nodeP, e2n);

  // head
  k_final<<<(NN+31)/32, 256, 0, stream>>>(e2n, Wo, bo, gid, yacc);
  k_out<<<(NG*D)/256, 256, 0, stream>>>(yacc, (float*)d_out);
}

// Round 2
// 673.693 us; speedup vs baseline: 1.0479x; 1.0479x over previous
//
#include <hip/hip_runtime.h>

// EmbedLoopyBP on gfx950 — round 10.
// Hybrid of R8 (traffic profile) + R9 (barrier-free structure):
//  - Wc^T/We^T pre-arranged in MFMA B-fragment order in global (L1-hot,
//    8KB/4KB) -> zero barriers in k_iter/k_im, bank conflicts 4.4M->1.2M.
//  - naW consumed as bf16 (naWb) via k_cvt passes (R9's fp32 direct read
//    added +45MB FETCH = +14us/dispatch at the measured ~3.2TB/s).
// k_iter behaves traffic-proportional at ~3.1-3.2 TB/s of L2-miss bytes.

#define NN 50000
#define NE 800000
#define NG 128
#define D 64
#define LDE 36
#define LDW 66
#define LDO 72

typedef unsigned short u16;
typedef unsigned int u32;
typedef __bf16 bf16x8 __attribute__((ext_vector_type(8)));
typedef float f32x4 __attribute__((ext_vector_type(4)));

__device__ __forceinline__ float b2f(u16 u){ u32 x=((u32)u)<<16; float f; __builtin_memcpy(&f,&x,4); return f; }
__device__ __forceinline__ u16 f2b(float f){ u32 x; __builtin_memcpy(&x,&f,4); x += 0x7fffu + ((x>>16)&1u); return (u16)(x>>16); }
__device__ __forceinline__ u32 pack2(float a, float b){ return (u32)f2b(a) | ((u32)f2b(b)<<16); }
__device__ __forceinline__ void unpack8(uint4 v, float* o){
  o[0]=b2f((u16)(v.x&0xffffu)); o[1]=b2f((u16)(v.x>>16));
  o[2]=b2f((u16)(v.y&0xffffu)); o[3]=b2f((u16)(v.y>>16));
  o[4]=b2f((u16)(v.z&0xffffu)); o[5]=b2f((u16)(v.z>>16));
  o[6]=b2f((u16)(v.w&0xffffu)); o[7]=b2f((u16)(v.w>>16));
}

// ---------------- one-time weight fragment-order convert ----------------
// wcB[nt][h][j][kk] (4x2x64x8 u16): lane j loads its B fragment for tile nt,
// K-half h as 8 contiguous bf16 at wcB+nt*1024+h*512+j*8.
//   j=q*16+mr; element kk -> Wc[(h*32+q*8+kk)*D + nt*16+mr]
// weB[nt][j][kk] (4x64x8 u16): K=32, element kk -> We[(q*8+kk)*D + nt*16+mr]
__global__ __launch_bounds__(256) void k_prep(const float* __restrict__ Wc, const float* __restrict__ We,
                                              u16* __restrict__ wcB, u16* __restrict__ weB){
  int i = blockIdx.x*256 + threadIdx.x;
  if (i < 4096){
    int nt = i>>10, r = i&1023;
    int h = r>>9, r2 = r&511;
    int j = r2>>3, kk = r2&7;
    int row = nt*16 + (j&15);
    int k = h*32 + (j>>4)*8 + kk;
    wcB[i] = f2b(Wc[k*D + row]);
  }
  int t = i - 4096;
  if (t >= 0 && t < 2048){
    int nt = t>>9, r = t&511;
    int j = r>>3, kk = r&7;
    int row = nt*16 + (j&15);
    int k = (j>>4)*8 + kk;
    weB[t] = f2b(We[k*D + row]);
  }
}

// ---------------- naW fp32 -> bf16 (+ optional re-zero of another buffer) ----------------
template<int ZERO>
__global__ __launch_bounds__(256) void k_cvt(const float* __restrict__ srcv, u16* __restrict__ dstb,
                                             float* __restrict__ zbuf){
  size_t i = (size_t)(blockIdx.x*256 + threadIdx.x)*4;
  float4 v = *(const float4*)(srcv + i);
  *(uint2*)(dstb + i) = make_uint2(pack2(v.x,v.y), pack2(v.z,v.w));
  if (ZERO) *(float4*)(zbuf + i) = make_float4(0.f,0.f,0.f,0.f);
}

// ---------------- node linear: inlb = bf16(node_feat @ Wn + bn) ----------------
__global__ __launch_bounds__(256) void k_inl(const float* __restrict__ nf, const float* __restrict__ Wn,
                                             const float* __restrict__ bn, u16* __restrict__ inlb){
  __shared__ float w[D*D];
  for (int i=threadIdx.x;i<D*D;i+=256) w[i]=Wn[i];
  __syncthreads();
  const int d = threadIdx.x&63;
  const int n = blockIdx.x*4 + (threadIdx.x>>6);
  if (n>=NN) return;
  float v = bn[d];
  const float* row = nf + (size_t)n*D;
  #pragma unroll 8
  for (int k=0;k<D;k++) v += row[k]*w[k*D+d];
  inlb[(size_t)n*D+d] = f2b(v);
}

// ---------------- imP[perm[e]] = edge_feat@We + be + inl[src[e]]  (bf16) ----------------
// barrier-free: efs/os rows wave-local; B from global weB (L1-hot)
__global__ __launch_bounds__(256) void k_im(const float* __restrict__ ef, const u16* __restrict__ weB,
                                            const float* __restrict__ be, const u16* __restrict__ inlb,
                                            const int* __restrict__ src, const int* __restrict__ perm,
                                            u16* __restrict__ imP){
  __shared__ __align__(16) u16 efs[64*LDE];
  __shared__ float os[64*68];
  const int t = threadIdx.x;
  const int ebase = blockIdx.x*64;
  { // stage edge_feat bf16 (coalesced float4 reads); wave-local rows
    int e=t>>2, k0=(t&3)*8;
    const float* p = ef + (size_t)(ebase+e)*32 + k0;
    float4 v0=*(const float4*)p, v1=*(const float4*)(p+4);
    uint4 pk = make_uint4(pack2(v0.x,v0.y),pack2(v0.z,v0.w),pack2(v1.x,v1.y),pack2(v1.z,v1.w));
    *(uint4*)&efs[e*LDE + k0] = pk;
  }
  { // MFMA 16x16x32 (K=32, one step); B fragments from global, coalesced
    int w=t>>6, lane=t&63, q=lane>>4, mr=lane&15;
    int rowb=w*16;
    bf16x8 A = *(const bf16x8*)&efs[(rowb+mr)*LDE + q*8];
    #pragma unroll
    for (int nt=0;nt<4;nt++){
      bf16x8 B = *(const bf16x8*)(weB + nt*512 + lane*8);
      f32x4 acc = {0.f,0.f,0.f,0.f};
      acc = __builtin_amdgcn_mfma_f32_16x16x32_bf16(A,B,acc,0,0,0);
      #pragma unroll
      for (int r=0;r<4;r++) os[(rowb+q*4+r)*68 + nt*16+mr] = acc[r];
    }
  }
  { // epilogue: + be + inlb[src[e]] -> bf16, full-row scatter to imP[perm[e]]
    int e=t>>2, d0=(t&3)*16;
    const size_t eg = (size_t)(ebase+e);
    const int s = src[eg], ps = perm[eg];
    const u16* ip = inlb + (size_t)s*D + d0;
    uint4 iv0 = *(const uint4*)ip, iv1 = *(const uint4*)(ip+8);
    float il[16]; unpack8(iv0,il); unpack8(iv1,il+8);
    float x[16];
    #pragma unroll
    for (int j=0;j<16;j++) x[j] = os[e*68 + d0 + j] + be[d0+j] + il[j];
    uint4 p0 = make_uint4(pack2(x[0],x[1]),pack2(x[2],x[3]),pack2(x[4],x[5]),pack2(x[6],x[7]));
    uint4 p1 = make_uint4(pack2(x[8],x[9]),pack2(x[10],x[11]),pack2(x[12],x[13]),pack2(x[14],x[15]));
    u16* op = imP + (size_t)ps*D + d0;
    *(uint4*)op = p0; *(uint4*)(op+8) = p1;
  }
}

// ---------------- iteration kernel: 64 slots/block, ZERO barriers ----------------
// MODE 0: x=relu(imP[slot]);                                revOut[prevP[slot]]=(x@Wc); naW_out += per-node
// MODE 1: x=relu(naWb[srcP] (bf16) - revIn[slot]+bc+imP[slot]); same outputs
template<int MODE>
__global__ __launch_bounds__(256) void k_iter(const u16* __restrict__ imP, const u16* __restrict__ revIn,
      const u16* __restrict__ naWb, const u16* __restrict__ wcB, const float* __restrict__ bc,
      const int* __restrict__ srcP, const int* __restrict__ prevP, const int* __restrict__ nodeP,
      u16* __restrict__ revOut, float* __restrict__ naW_out){
  __shared__ __align__(16) u16 xs[64*LDW];
  __shared__ __align__(16) u16 os[64*LDO];
  __shared__ int nid[64];
  const int t = threadIdx.x;
  const int lane = t&63, w = t>>6;
  const size_t sbase = (size_t)blockIdx.x*64;
  if (lane < 16) nid[w*16 + lane] = nodeP[sbase + w*16 + lane];   // wave-local
  { // phase 1: stream reads + bf16 naWb row gather; xs rows wave-local
    const int e = t>>2, d0 = (t&3)*16;
    const size_t slot = sbase + e;
    const u16* ip = imP + slot*D + d0;
    uint4 r0 = *(const uint4*)ip, r1 = *(const uint4*)(ip+8);
    float x[16]; unpack8(r0,x); unpack8(r1,x+8);
    if (MODE == 1){
      const int sp = srcP[slot];
      const u16* cp = revIn + slot*D + d0;
      uint4 c0=*(const uint4*)cp, c1=*(const uint4*)(cp+8);
      const u16* np_ = naWb + (size_t)sp*D + d0;
      uint4 n0=*(const uint4*)np_, n1=*(const uint4*)(np_+8);
      float cv[16], nv[16];
      unpack8(c0,cv); unpack8(c1,cv+8);
      unpack8(n0,nv); unpack8(n1,nv+8);
      #pragma unroll
      for (int j=0;j<16;j++) x[j] += nv[j] - cv[j] + bc[d0+j];
    }
    #pragma unroll
    for (int j=0;j<16;j++) x[j] = x[j]>0.f ? x[j] : 0.f;
    uint4 p0 = make_uint4(pack2(x[0],x[1]),pack2(x[2],x[3]),pack2(x[4],x[5]),pack2(x[6],x[7]));
    uint4 p1 = make_uint4(pack2(x[8],x[9]),pack2(x[10],x[11]),pack2(x[12],x[13]),pack2(x[14],x[15]));
    u16* qd = &xs[e*LDW + d0];
    *(uint4*)qd = p0; *(uint4*)(qd+8) = p1;
  }
  { // phase 2: MFMA (xs wave-local, within-wave LDS ordering); B from global wcB
    const int q = lane>>4, mr = lane&15;
    const int rowb = w*16;
    bf16x8 A0 = *(const bf16x8*)&xs[(rowb+mr)*LDW + q*8];
    bf16x8 A1 = *(const bf16x8*)&xs[(rowb+mr)*LDW + 32 + q*8];
    #pragma unroll
    for (int nt=0;nt<4;nt++){
      bf16x8 B0 = *(const bf16x8*)(wcB + nt*1024 + lane*8);
      bf16x8 B1 = *(const bf16x8*)(wcB + nt*1024 + 512 + lane*8);
      f32x4 acc = {0.f,0.f,0.f,0.f};
      acc = __builtin_amdgcn_mfma_f32_16x16x32_bf16(A0,B0,acc,0,0,0);
      acc = __builtin_amdgcn_mfma_f32_16x16x32_bf16(A1,B1,acc,0,0,0);
      #pragma unroll
      for (int r=0;r<4;r++) os[(rowb+q*4+r)*LDO + nt*16 + mr] = f2b(acc[r]);
    }
    const int lr = lane>>2, cc = lane&3;
    const int tgt = prevP[sbase + rowb + lr];
    u16* gp = revOut + (size_t)tgt*D + cc*16;
    *(uint4*)gp     = *(const uint4*)&os[(rowb+lr)*LDO + cc*16];
    *(uint4*)(gp+8) = *(const uint4*)&os[(rowb+lr)*LDO + cc*16 + 8];
    // fused per-node reduction (wave-local os + nid)
    float acc = 0.f;
    int curn = nid[rowb];
    #pragma unroll 4
    for (int i=0;i<16;++i){
      int n = nid[rowb+i];                 // wave-uniform
      if (n != curn){
        atomicAdd(&naW_out[(size_t)curn*D + lane], acc);
        curn = n; acc = 0.f;
      }
      acc += b2f(os[(rowb+i)*LDO + lane]);
    }
    atomicAdd(&naW_out[(size_t)curn*D + lane], acc);
  }
}

// ---------------- final BP step (barrier-free): e2n += per-node ----------------
__global__ __launch_bounds__(256) void k_last(const u16* __restrict__ imP, const u16* __restrict__ revIn,
      const u16* __restrict__ naWb, const float* __restrict__ bc,
      const int* __restrict__ srcP, const int* __restrict__ nodeP,
      float* __restrict__ e2n){
  __shared__ __align__(16) u16 xs[64*LDW];
  __shared__ int nid[64];
  const int t = threadIdx.x;
  const int lane = t&63, w = t>>6;
  const size_t sbase = (size_t)blockIdx.x*64;
  if (lane < 16) nid[w*16+lane] = nodeP[sbase + w*16 + lane];   // wave-local
  {
    const int e = t>>2, d0 = (t&3)*16;
    const size_t slot = sbase + e;
    const u16* ip = imP + slot*D + d0;
    uint4 r0 = *(const uint4*)ip, r1 = *(const uint4*)(ip+8);
    float x[16]; unpack8(r0,x); unpack8(r1,x+8);
    const int sp = srcP[slot];
    const u16* cp = revIn + slot*D + d0;
    uint4 c0 = *(const uint4*)cp, c1 = *(const uint4*)(cp+8);
    const u16* np_ = naWb + (size_t)sp*D + d0;
    uint4 n0 = *(const uint4*)np_, n1 = *(const uint4*)(np_+8);
    float cv[16], nv[16];
    unpack8(c0,cv); unpack8(c1,cv+8);
    unpack8(n0,nv); unpack8(n1,nv+8);
    #pragma unroll
    for (int j=0;j<16;j++){ x[j] += nv[j] - cv[j] + bc[d0+j]; x[j] = x[j]>0.f ? x[j] : 0.f; }
    uint4 p0 = make_uint4(pack2(x[0],x[1]),pack2(x[2],x[3]),pack2(x[4],x[5]),pack2(x[6],x[7]));
    uint4 p1 = make_uint4(pack2(x[8],x[9]),pack2(x[10],x[11]),pack2(x[12],x[13]),pack2(x[14],x[15]));
    u16* qd = &xs[e*LDW + d0];
    *(uint4*)qd = p0; *(uint4*)(qd+8) = p1;
  }
  { // wave-local reduction, no barrier
    float acc = 0.f;
    int curn = nid[w*16];
    #pragma unroll 4
    for (int i=0;i<16;++i){
      int n = nid[w*16+i];
      if (n != curn){
        atomicAdd(&e2n[(size_t)curn*D + lane], acc);
        curn = n; acc = 0.f;
      }
      acc += b2f(xs[(w*16+i)*LDW + lane]);
    }
    atomicAdd(&e2n[(size_t)curn*D + lane], acc);
  }
}

// ---------------- CSR build ----------------
__global__ void k_hist(const int* __restrict__ dst, int* __restrict__ cnt){
  int e = blockIdx.x*256 + threadIdx.x;
  atomicAdd(&cnt[dst[e]], 1);
}
__global__ __launch_bounds__(1024) void k_scan1(const int* __restrict__ cnt, int* __restrict__ outv,
                                                int* __restrict__ bsums, int n){
  __shared__ int sh[1024];
  int i = blockIdx.x*1024 + threadIdx.x;
  int v = (i<n)? cnt[i] : 0;
  sh[threadIdx.x]=v;
  __syncthreads();
  for (int off=1; off<1024; off<<=1){
    int tv = (threadIdx.x>=(unsigned)off)? sh[threadIdx.x-off] : 0;
    __syncthreads();
    sh[threadIdx.x] += tv;
    __syncthreads();
  }
  if (i<n) outv[i] = sh[threadIdx.x] - v;
  if (threadIdx.x==1023) bsums[blockIdx.x] = sh[1023];
}
__global__ __launch_bounds__(1024) void k_scan3(int* __restrict__ off, int* __restrict__ cur,
                                                const int* __restrict__ bsums, int n){
  __shared__ int spref;
  if (threadIdx.x < 64){
    int v = ((int)threadIdx.x < (int)blockIdx.x) ? bsums[threadIdx.x] : 0;
    #pragma unroll
    for (int o=1;o<64;o<<=1) v += __shfl_xor(v, o, 64);
    if (threadIdx.x==0) spref = v;
  }
  __syncthreads();
  int i = blockIdx.x*1024 + threadIdx.x;
  if (i<n){ int v = off[i] + spref; off[i]=v; cur[i]=v; }
}
__global__ void k_fill(const int* __restrict__ dst, const int* __restrict__ src,
                       int* __restrict__ cur, int* __restrict__ perm,
                       int* __restrict__ srcP, int* __restrict__ nodeP){
  int e = blockIdx.x*256 + threadIdx.x;
  int d = dst[e];
  int pos = atomicAdd(&cur[d], 1);
  perm[e] = pos;
  srcP[pos] = src[e];
  nodeP[pos] = d;
}
__global__ void k_prev(const int* __restrict__ rev, const int* __restrict__ perm, int* __restrict__ prevP){
  int e = blockIdx.x*256 + threadIdx.x;
  prevP[perm[e]] = perm[rev[e]];
}

// ---------------- final: relu(e2n)@Wo+bo -> relu -> graph segsum ----------------
__global__ __launch_bounds__(256) void k_final(const float* __restrict__ e2n, const float* __restrict__ Wo,
                                               const float* __restrict__ bo, const int* __restrict__ gid,
                                               float* __restrict__ yacc){
  __shared__ float w[D*D];
  for (int i=threadIdx.x;i<D*D;i+=256) w[i]=Wo[i];
  __syncthreads();
  const int d = threadIdx.x&63, sub = threadIdx.x>>6;
  const int n0 = blockIdx.x*32 + sub*8;
  const float bod = bo[d];
  float acc=0.f; int curg=-1;
  for (int i=0;i<8;i++){
    int n=n0+i;
    if (n>=NN) break;
    int g = gid[n];
    if (g!=curg){ if (curg>=0) atomicAdd(&yacc[curg*D+d], acc); curg=g; acc=0.f; }
    float v=bod;
    const float* er = e2n + (size_t)n*D;
    #pragma unroll 8
    for (int k=0;k<D;k++){ float h=er[k]; h = h>0.f?h:0.f; v += h*w[k*D+d]; }
    acc += (v>0.f ? v : 0.f);
  }
  if (curg>=0) atomicAdd(&yacc[curg*D+d], acc);
}
__global__ void k_out(const float* __restrict__ yacc, float* __restrict__ outp){
  int i = blockIdx.x*256 + threadIdx.x;
  if (i<NG*D){ float v=yacc[i]; outp[i]= v>0.f?v:0.f; }
}

// ---------------- workspace layout ----------------
static constexpr size_t SZ_E   = (size_t)NE*D*2;          // 102.4 MB bf16 edge array
static constexpr size_t SZ_NF4 = (size_t)NN*D*4;          // 12.8 MB fp32 node array
static constexpr size_t SZ_NB  = (size_t)NN*D*2;          // 6.4 MB bf16 node array
static constexpr size_t OFF_IMP  = 0;
static constexpr size_t OFF_RVA  = SZ_E;
static constexpr size_t OFF_RVB  = 2*SZ_E;
// contiguous zero region: csr_cur | naW0 | naW1 | e2n | yacc
static constexpr size_t OFF_CCUR = 3*SZ_E;
static constexpr size_t OFF_NA0  = OFF_CCUR + 200064;
static constexpr size_t OFF_NA1  = OFF_NA0 + SZ_NF4;
static constexpr size_t OFF_E2N  = OFF_NA1 + SZ_NF4;
static constexpr size_t OFF_YACC = OFF_E2N + SZ_NF4;
static constexpr size_t ZERO_SZ  = 200064 + 3*SZ_NF4 + (size_t)NG*D*4;
static constexpr size_t OFF_NAB  = OFF_YACC + (size_t)NG*D*4;   // bf16 naW (single reused buffer)
static constexpr size_t OFF_INL  = OFF_NAB + SZ_NB;
static constexpr size_t OFF_COFF = OFF_INL + SZ_NB;
static constexpr size_t OFF_PERM = OFF_COFF + 200064;
static constexpr size_t OFF_SRCP = OFF_PERM + (size_t)NE*4;
static constexpr size_t OFF_PRVP = OFF_SRCP + (size_t)NE*4;
static constexpr size_t OFF_NODP = OFF_PRVP + (size_t)NE*4;
static constexpr size_t OFF_BS   = OFF_NODP + (size_t)NE*4;
static constexpr size_t OFF_WCT  = OFF_BS + 256;               // wcB: 4096 u16 = 8192 B
static constexpr size_t OFF_WET  = OFF_WCT + 8192;             // weB: 2048 u16 = 4096 B

extern "C" void kernel_launch(void* const* d_in, const int* in_sizes, int n_in,
                              void* d_out, int out_size, void* d_ws, size_t ws_size,
                              hipStream_t stream) {
  const float* node_feat = (const float*)d_in[0];
  const float* edge_feat = (const float*)d_in[1];
  const int*   src       = (const int*)d_in[2];
  const int*   dst       = (const int*)d_in[3];
  const int*   rev       = (const int*)d_in[4];
  const int*   gid       = (const int*)d_in[5];
  const float* Wn = (const float*)d_in[7];
  const float* bn = (const float*)d_in[8];
  const float* We = (const float*)d_in[9];
  const float* be = (const float*)d_in[10];
  const float* Wc = (const float*)d_in[11];
  const float* bc = (const float*)d_in[12];
  const float* Wo = (const float*)d_in[13];
  const float* bo = (const float*)d_in[14];

  char* ws = (char*)d_ws;
  u16*   imP     = (u16*)(ws + OFF_IMP);
  u16*   revA    = (u16*)(ws + OFF_RVA);
  u16*   revB    = (u16*)(ws + OFF_RVB);
  float* naW0    = (float*)(ws + OFF_NA0);
  float* naW1    = (float*)(ws + OFF_NA1);
  float* e2n     = (float*)(ws + OFF_E2N);
  float* yacc    = (float*)(ws + OFF_YACC);
  u16*   naWb    = (u16*)(ws + OFF_NAB);
  u16*   inlb    = (u16*)(ws + OFF_INL);
  int*   csr_off = (int*)(ws + OFF_COFF);
  int*   csr_cur = (int*)(ws + OFF_CCUR);
  int*   perm    = (int*)(ws + OFF_PERM);
  int*   srcP    = (int*)(ws + OFF_SRCP);
  int*   prevP   = (int*)(ws + OFF_PRVP);
  int*   nodeP   = (int*)(ws + OFF_NODP);
  int*   bsums   = (int*)(ws + OFF_BS);
  u16*   wcB     = (u16*)(ws + OFF_WCT);
  u16*   weB     = (u16*)(ws + OFF_WET);

  // one upfront memset: csr_cur + naW0 + naW1 + e2n + yacc
  hipMemsetAsync(ws + OFF_CCUR, 0, ZERO_SZ, stream);

  // CSR build
  k_hist <<<NE/256, 256, 0, stream>>>(dst, csr_cur);
  k_scan1<<<49, 1024, 0, stream>>>(csr_cur, csr_off, bsums, NN);
  k_scan3<<<49, 1024, 0, stream>>>(csr_off, csr_cur, bsums, NN);
  k_fill <<<NE/256, 256, 0, stream>>>(dst, src, csr_cur, perm, srcP, nodeP);
  k_prev <<<NE/256, 256, 0, stream>>>(rev, perm, prevP);

  // weights prep + front end
  k_prep<<<24, 256, 0, stream>>>(Wc, We, wcB, weB);
  k_inl <<<NN/4, 256, 0, stream>>>(node_feat, Wn, bn, inlb);
  k_im  <<<NE/64, 256, 0, stream>>>(edge_feat, weB, be, inlb, src, perm, imP);

  // loopy BP (bf16 naWb consumption; k_cvt converts + fuses re-zero)
  k_iter<0><<<NE/64, 256, 0, stream>>>(imP, revA, naWb, wcB, bc, srcP, prevP, nodeP, revA, naW0);
  k_cvt<0><<<3125, 256, 0, stream>>>(naW0, naWb, (float*)nullptr);
  k_iter<1><<<NE/64, 256, 0, stream>>>(imP, revA, naWb, wcB, bc, srcP, prevP, nodeP, revB, naW1);
  k_cvt<1><<<3125, 256, 0, stream>>>(naW1, naWb, naW0);     // convert + re-zero naW0
  k_iter<1><<<NE/64, 256, 0, stream>>>(imP, revB, naWb, wcB, bc, srcP, prevP, nodeP, revA, naW0);
  k_cvt<0><<<3125, 256, 0, stream>>>(naW0, naWb, (float*)nullptr);
  k_last<<<NE/64, 256, 0, stream>>>(imP, revA, naWb, bc, srcP, nodeP, e2n);

  // head
  k_final<<<(NN+31)/32, 256, 0, stream>>>(e2n, Wo, bo, gid, yacc);
  k_out<<<(NG*D)/256, 256, 0, stream>>>(yacc, (float*)d_out);
}